// Round 1
// baseline (478.276 us; speedup 1.0000x reference)
//
#include <hip/hip_runtime.h>
#include <hip/hip_fp16.h>
#include <cstdint>

typedef _Float16 f16x8 __attribute__((ext_vector_type(8)));
typedef _Float16 f16x4 __attribute__((ext_vector_type(4)));
typedef float    f32x4 __attribute__((ext_vector_type(4)));

#define MFMA16(a, b, c) __builtin_amdgcn_mfma_f32_16x16x32_f16((a), (b), (c), 0, 0, 0)

// B=4, LQ=4096, LKV=256, D=1024, H=16, KVH=4, HD=64

// ---------------------------------------------------------------------------
// Transpose + fp32->fp16 convert: W[Kd][Nd] (row-major) -> WT[Nd][Kd]
// ---------------------------------------------------------------------------
__global__ __launch_bounds__(256) void transpose_cvt(const float* __restrict__ W,
                                                     _Float16* __restrict__ WT,
                                                     int Kd, int Nd) {
    __shared__ float T[64][65];
    const int n0 = blockIdx.x * 64, k0 = blockIdx.y * 64;
    const int tid = threadIdx.x;
    const int nl = tid & 63, kg = tid >> 6;
#pragma unroll
    for (int i = 0; i < 16; ++i) {
        const int kl = kg * 16 + i;
        T[kl][nl] = W[(size_t)(k0 + kl) * Nd + n0 + nl];
    }
    __syncthreads();
    const int kl = tid & 63;
#pragma unroll
    for (int i = 0; i < 16; ++i) {
        const int nl2 = kg * 16 + i;
        WT[(size_t)(n0 + nl2) * Kd + k0 + kl] = (_Float16)T[kl][nl2];
    }
}

// ---------------------------------------------------------------------------
// GEMM: C(M x N) = A(M x K) @ BT(N x K)^T + bias, fused epilogues.
//   AF16: 0 = A is fp32 (convert on stage), 1 = A is fp16
//   EPI:  0 = Q-proj (bias, RoPE, *0.125, fp16 [b,h,lq,hd])
//         1 = K-proj (bias, RoPE, fp16 [b,kvh,lkv,hd])
//         2 = V-proj (bias, fp16 transposed [b,kvh,hd,lkv])
//         3 = O-proj (bias, fp32 row-major out)
// Tile 128x128, BK=32, 4 waves in 2x2, each wave 64x64 (4x4 16x16 frags).
// All dims assumed divisible (they are for this problem).
// ---------------------------------------------------------------------------
template <int AF16, int EPI>
__global__ __launch_bounds__(256) void gemm_k(const void* __restrict__ Ap,
                                              const _Float16* __restrict__ BT,
                                              const float* __restrict__ bias,
                                              void* __restrict__ Cp,
                                              int K, int N,
                                              const int* __restrict__ nfp) {
    __shared__ _Float16 As[128][40];  // +8 pad: 80B rows, 16B-aligned, 2-way banks
    __shared__ _Float16 Bs[128][40];

    const int tid  = threadIdx.x;
    const int lane = tid & 63, quad = lane >> 4, l15 = lane & 15;
    const int w = tid >> 6, wm = w >> 1, wn = w & 1;
    const int n0 = blockIdx.x * 128;
    const int m0 = blockIdx.y * 128;

    f32x4 acc[4][4];
#pragma unroll
    for (int mt = 0; mt < 4; ++mt)
#pragma unroll
        for (int nt = 0; nt < 4; ++nt) {
            f32x4 z = {0.f, 0.f, 0.f, 0.f};
            acc[mt][nt] = z;
        }

    for (int k0 = 0; k0 < K; k0 += 32) {
        // ---- stage A tile (128 x 32)
        if (AF16 == 0) {
            const float* A = (const float*)Ap;
#pragma unroll
            for (int i = 0; i < 4; ++i) {
                const int idx = tid + 256 * i;
                const int r = idx >> 3, c = idx & 7;
                const float4 v = *(const float4*)(A + (size_t)(m0 + r) * K + k0 + c * 4);
                f16x4 hv;
                hv[0] = (_Float16)v.x; hv[1] = (_Float16)v.y;
                hv[2] = (_Float16)v.z; hv[3] = (_Float16)v.w;
                *(f16x4*)&As[r][c * 4] = hv;
            }
        } else {
            const _Float16* A = (const _Float16*)Ap;
#pragma unroll
            for (int i = 0; i < 2; ++i) {
                const int idx = tid + 256 * i;
                const int r = idx >> 2, c = idx & 3;
                *(f16x8*)&As[r][c * 8] =
                    *(const f16x8*)(A + (size_t)(m0 + r) * K + k0 + c * 8);
            }
        }
        // ---- stage B tile (128 n-rows x 32 k), BT already [n][k] fp16
#pragma unroll
        for (int i = 0; i < 2; ++i) {
            const int idx = tid + 256 * i;
            const int r = idx >> 2, c = idx & 3;
            *(f16x8*)&Bs[r][c * 8] =
                *(const f16x8*)(BT + (size_t)(n0 + r) * K + k0 + c * 8);
        }
        __syncthreads();

        f16x8 af[4], bf[4];
#pragma unroll
        for (int mt = 0; mt < 4; ++mt)
            af[mt] = *(const f16x8*)&As[wm * 64 + mt * 16 + l15][quad * 8];
#pragma unroll
        for (int nt = 0; nt < 4; ++nt)
            bf[nt] = *(const f16x8*)&Bs[wn * 64 + nt * 16 + l15][quad * 8];
#pragma unroll
        for (int mt = 0; mt < 4; ++mt)
#pragma unroll
            for (int nt = 0; nt < 4; ++nt)
                acc[mt][nt] = MFMA16(af[mt], bf[nt], acc[mt][nt]);
        __syncthreads();
    }

    // ---- epilogue: bias
    float bb[4];
#pragma unroll
    for (int nt = 0; nt < 4; ++nt) bb[nt] = bias[n0 + wn * 64 + nt * 16 + l15];
#pragma unroll
    for (int mt = 0; mt < 4; ++mt)
#pragma unroll
        for (int nt = 0; nt < 4; ++nt)
#pragma unroll
            for (int rr = 0; rr < 4; ++rr) acc[mt][nt][rr] += bb[nt];

    // ---- RoPE (Q/K only). Wave spans exactly one 64-wide head: hd = nt*16+l15.
    // Pairs (hd, hd+32) = frags (nt, nt+2); cos/sin depend on (pos, hd&31).
    if (EPI == 0 || EPI == 1) {
        const int nf = nfp[0];
        if (nf > 1) {
            const int L  = (EPI == 0) ? 4096 : 256;
            const int dv = L / nf;
            const float l2b  = 13.287712379549449f;  // log2(10000)
            const float inv0 = exp2f(-((float)l15 * (1.0f / 32.0f)) * l2b);
            const float inv1 = exp2f(-((float)(l15 + 16) * (1.0f / 32.0f)) * l2b);
#pragma unroll
            for (int mt = 0; mt < 4; ++mt) {
#pragma unroll
                for (int rr = 0; rr < 4; ++rr) {
                    const int m   = m0 + wm * 64 + mt * 16 + quad * 4 + rr;
                    const int ll  = m & (L - 1);
                    const int pos = ll / dv;
                    float s0, c0, s1, c1;
                    __sincosf((float)pos * inv0, &s0, &c0);
                    __sincosf((float)pos * inv1, &s1, &c1);
                    float x1 = acc[mt][0][rr], x2 = acc[mt][2][rr];
                    acc[mt][0][rr] = x1 * c0 - x2 * s0;
                    acc[mt][2][rr] = x2 * c0 + x1 * s0;
                    x1 = acc[mt][1][rr]; x2 = acc[mt][3][rr];
                    acc[mt][1][rr] = x1 * c1 - x2 * s1;
                    acc[mt][3][rr] = x2 * c1 + x1 * s1;
                }
            }
        }
    }

    // ---- stores
    if (EPI == 0) {  // q_h[b][h][lq][hd], scale 1/8 folded in
        _Float16* O = (_Float16*)Cp;
#pragma unroll
        for (int mt = 0; mt < 4; ++mt)
#pragma unroll
            for (int rr = 0; rr < 4; ++rr) {
                const int m = m0 + wm * 64 + mt * 16 + quad * 4 + rr;
                const int b = m >> 12, lq = m & 4095;
#pragma unroll
                for (int nt = 0; nt < 4; ++nt) {
                    const int n = n0 + wn * 64 + nt * 16 + l15;
                    const int h = n >> 6, hd = n & 63;
                    O[(((size_t)(b * 16 + h)) * 4096 + lq) * 64 + hd] =
                        (_Float16)(acc[mt][nt][rr] * 0.125f);
                }
            }
    } else if (EPI == 1) {  // k_h[b][kvh][lkv][hd]
        _Float16* O = (_Float16*)Cp;
#pragma unroll
        for (int mt = 0; mt < 4; ++mt)
#pragma unroll
            for (int rr = 0; rr < 4; ++rr) {
                const int m = m0 + wm * 64 + mt * 16 + quad * 4 + rr;
                const int b = m >> 8, lkv = m & 255;
#pragma unroll
                for (int nt = 0; nt < 4; ++nt) {
                    const int n = n0 + wn * 64 + nt * 16 + l15;
                    const int kvh = n >> 6, hd = n & 63;
                    O[(((size_t)(b * 4 + kvh)) * 256 + lkv) * 64 + hd] =
                        (_Float16)acc[mt][nt][rr];
                }
            }
    } else if (EPI == 2) {  // v_t[b][kvh][hd][lkv]  (transposed for PV B-operand)
        _Float16* O = (_Float16*)Cp;
#pragma unroll
        for (int mt = 0; mt < 4; ++mt)
#pragma unroll
            for (int rr = 0; rr < 4; ++rr) {
                const int m = m0 + wm * 64 + mt * 16 + quad * 4 + rr;
                const int b = m >> 8, lkv = m & 255;
#pragma unroll
                for (int nt = 0; nt < 4; ++nt) {
                    const int n = n0 + wn * 64 + nt * 16 + l15;
                    const int kvh = n >> 6, hd = n & 63;
                    O[(((size_t)(b * 4 + kvh)) * 64 + hd) * 256 + lkv] =
                        (_Float16)acc[mt][nt][rr];
                }
            }
    } else {  // O-proj: fp32 row-major
        float* O = (float*)Cp;
#pragma unroll
        for (int mt = 0; mt < 4; ++mt)
#pragma unroll
            for (int rr = 0; rr < 4; ++rr) {
                const int m = m0 + wm * 64 + mt * 16 + quad * 4 + rr;
#pragma unroll
                for (int nt = 0; nt < 4; ++nt) {
                    const int n = n0 + wn * 64 + nt * 16 + l15;
                    O[(size_t)m * N + n] = acc[mt][nt][rr];
                }
            }
    }
}

// ---------------------------------------------------------------------------
// Attention: one block = 64 q-rows of one (b,h). LKV=256 fits -> two-pass
// softmax, no tiling. Q/K/Vt frags straight from global (K/V are L2-hot).
// P round-trips through LDS (C-layout -> A-operand layout).
// ---------------------------------------------------------------------------
__global__ __launch_bounds__(256) void attn_kernel(const _Float16* __restrict__ qh,
                                                   const _Float16* __restrict__ kh,
                                                   const _Float16* __restrict__ vt,
                                                   _Float16* __restrict__ attn) {
    __shared__ _Float16 Pl[4][16][264];  // per-wave P: 16 rows x 256 (+8 pad)

    const int tid = threadIdx.x;
    const int w = tid >> 6, lane = tid & 63, quad = lane >> 4, l15 = lane & 15;
    const int qt = blockIdx.x, bh = blockIdx.y;
    const int b = bh >> 4, h = bh & 15, kvh = h >> 2;

    // Q a-frags (scale 1/8 already folded in at Q-proj)
    const _Float16* qp =
        qh + (((size_t)bh * 4096) + qt * 64 + w * 16 + l15) * 64 + quad * 8;
    const f16x8 aq0 = *(const f16x8*)qp;
    const f16x8 aq1 = *(const f16x8*)(qp + 32);

    // S = Q @ K^T : 16 n-tiles of 16 cols
    f32x4 s[16];
#pragma unroll
    for (int nt = 0; nt < 16; ++nt) {
        f32x4 z = {0.f, 0.f, 0.f, 0.f};
        s[nt] = z;
    }
    const _Float16* kb = kh + ((size_t)(b * 4 + kvh) * 256) * 64;
#pragma unroll
    for (int nt = 0; nt < 16; ++nt) {
        const _Float16* kp = kb + (nt * 16 + l15) * 64 + quad * 8;
        const f16x8 b0 = *(const f16x8*)kp;
        const f16x8 b1 = *(const f16x8*)(kp + 32);
        s[nt] = MFMA16(aq0, b0, s[nt]);
        s[nt] = MFMA16(aq1, b1, s[nt]);
    }

    // row-wise softmax over 256 cols; row r lives in {lanes sharing quad} x 16 tiles
    float rmax[4] = {-1e30f, -1e30f, -1e30f, -1e30f};
#pragma unroll
    for (int nt = 0; nt < 16; ++nt)
#pragma unroll
        for (int rr = 0; rr < 4; ++rr) rmax[rr] = fmaxf(rmax[rr], s[nt][rr]);
#pragma unroll
    for (int off = 1; off <= 8; off <<= 1)
#pragma unroll
        for (int rr = 0; rr < 4; ++rr)
            rmax[rr] = fmaxf(rmax[rr], __shfl_xor(rmax[rr], off, 64));

    float rsum[4] = {0.f, 0.f, 0.f, 0.f};
#pragma unroll
    for (int nt = 0; nt < 16; ++nt)
#pragma unroll
        for (int rr = 0; rr < 4; ++rr) {
            const float p = __expf(s[nt][rr] - rmax[rr]);
            rsum[rr] += p;
            Pl[w][quad * 4 + rr][nt * 16 + l15] = (_Float16)p;
        }
#pragma unroll
    for (int off = 1; off <= 8; off <<= 1)
#pragma unroll
        for (int rr = 0; rr < 4; ++rr) rsum[rr] += __shfl_xor(rsum[rr], off, 64);

    __syncthreads();

    // O = P @ V : 4 n-tiles (hd), k = 256 in 8 steps
    f32x4 o[4];
#pragma unroll
    for (int nt = 0; nt < 4; ++nt) {
        f32x4 z = {0.f, 0.f, 0.f, 0.f};
        o[nt] = z;
    }
    const _Float16* vb = vt + ((size_t)(b * 4 + kvh) * 64) * 256;
#pragma unroll
    for (int kk = 0; kk < 8; ++kk) {
        const f16x8 pa = *(const f16x8*)&Pl[w][l15][kk * 32 + quad * 8];
#pragma unroll
        for (int nt = 0; nt < 4; ++nt) {
            const f16x8 bv =
                *(const f16x8*)(vb + (nt * 16 + l15) * 256 + kk * 32 + quad * 8);
            o[nt] = MFMA16(pa, bv, o[nt]);
        }
    }

    float inv[4];
#pragma unroll
    for (int rr = 0; rr < 4; ++rr) inv[rr] = 1.0f / rsum[rr];
#pragma unroll
    for (int nt = 0; nt < 4; ++nt)
#pragma unroll
        for (int rr = 0; rr < 4; ++rr) {
            const int row = qt * 64 + w * 16 + quad * 4 + rr;
            attn[(((size_t)b * 4096) + row) * 1024 + h * 64 + nt * 16 + l15] =
                (_Float16)(o[nt][rr] * inv[rr]);
        }
}

// ---------------------------------------------------------------------------
extern "C" void kernel_launch(void* const* d_in, const int* in_sizes, int n_in,
                              void* d_out, int out_size, void* d_ws, size_t ws_size,
                              hipStream_t stream) {
    const float* patches = (const float*)d_in[0];
    const float* latents = (const float*)d_in[1];
    const float* Wq = (const float*)d_in[2];
    const float* bq = (const float*)d_in[3];
    const float* Wk = (const float*)d_in[4];
    const float* bk = (const float*)d_in[5];
    const float* Wv = (const float*)d_in[6];
    const float* bv = (const float*)d_in[7];
    const float* Wo = (const float*)d_in[8];
    const float* bo = (const float*)d_in[9];
    const int*   nf = (const int*)d_in[10];
    float* out = (float*)d_out;

    char* p = (char*)d_ws;
    _Float16* WqT = (_Float16*)p; p += (size_t)1024 * 1024 * 2;
    _Float16* WkT = (_Float16*)p; p += (size_t)256 * 1024 * 2;
    _Float16* WvT = (_Float16*)p; p += (size_t)256 * 1024 * 2;
    _Float16* WoT = (_Float16*)p; p += (size_t)1024 * 1024 * 2;
    _Float16* q_h = (_Float16*)p; p += (size_t)4 * 16 * 4096 * 64 * 2;
    _Float16* k_h = (_Float16*)p; p += (size_t)4 * 4 * 256 * 64 * 2;
    _Float16* v_t = (_Float16*)p; p += (size_t)4 * 4 * 256 * 64 * 2;
    _Float16* attn_h = (_Float16*)p; p += (size_t)16384 * 1024 * 2;
    (void)ws_size; (void)in_sizes; (void)n_in; (void)out_size;

    // weights -> fp16 [n][k]
    transpose_cvt<<<dim3(16, 16), 256, 0, stream>>>(Wq, WqT, 1024, 1024);
    transpose_cvt<<<dim3(4, 16), 256, 0, stream>>>(Wk, WkT, 1024, 256);
    transpose_cvt<<<dim3(4, 16), 256, 0, stream>>>(Wv, WvT, 1024, 256);
    transpose_cvt<<<dim3(16, 16), 256, 0, stream>>>(Wo, WoT, 1024, 1024);

    // projections (fused bias + RoPE + layout + scale)
    gemm_k<0, 0><<<dim3(8, 128), 256, 0, stream>>>(patches, WqT, bq, q_h, 1024, 1024, nf);
    gemm_k<0, 1><<<dim3(2, 8), 256, 0, stream>>>(latents, WkT, bk, k_h, 1024, 256, nf);
    gemm_k<0, 2><<<dim3(2, 8), 256, 0, stream>>>(latents, WvT, bv, v_t, 1024, 256, nf);

    // attention
    attn_kernel<<<dim3(64, 64), 256, 0, stream>>>(q_h, k_h, v_t, attn_h);

    // output projection
    gemm_k<1, 3><<<dim3(8, 128), 256, 0, stream>>>(attn_h, WoT, bo, out, 1024, 1024, nf);
}

// Round 2
// 379.603 us; speedup vs baseline: 1.2599x; 1.2599x over previous
//
#include <hip/hip_runtime.h>
#include <hip/hip_fp16.h>
#include <cstdint>

typedef _Float16 f16x8 __attribute__((ext_vector_type(8)));
typedef _Float16 f16x4 __attribute__((ext_vector_type(4)));
typedef float    f32x4 __attribute__((ext_vector_type(4)));
typedef float    f32x16 __attribute__((ext_vector_type(16)));

#define MFMA16(a, b, c) __builtin_amdgcn_mfma_f32_16x16x32_f16((a), (b), (c), 0, 0, 0)
#define MFMA32(a, b, c) __builtin_amdgcn_mfma_f32_32x32x16_f16((a), (b), (c), 0, 0, 0)

// B=4, LQ=4096, LKV=256, D=1024, H=16, KVH=4, HD=64

__device__ __forceinline__ void async_cp16(const _Float16* g, _Float16* l) {
    __builtin_amdgcn_global_load_lds(
        (const __attribute__((address_space(1))) void*)g,
        (__attribute__((address_space(3))) void*)l, 16, 0, 0);
}

// ---------------------------------------------------------------------------
// fp32 -> fp16 elementwise convert (float4 per thread)
// ---------------------------------------------------------------------------
__global__ __launch_bounds__(256) void cvt_f16(const float4* __restrict__ x,
                                               f16x4* __restrict__ y) {
    const int i = blockIdx.x * 256 + threadIdx.x;
    const float4 v = x[i];
    f16x4 o;
    o[0] = (_Float16)v.x; o[1] = (_Float16)v.y;
    o[2] = (_Float16)v.z; o[3] = (_Float16)v.w;
    y[i] = o;
}

// ---------------------------------------------------------------------------
// Transpose + fp32->fp16: W[Kd][Nd] -> WT[Nd][Kd]
// ---------------------------------------------------------------------------
__global__ __launch_bounds__(256) void transpose_cvt(const float* __restrict__ W,
                                                     _Float16* __restrict__ WT,
                                                     int Kd, int Nd) {
    __shared__ float T[64][65];
    const int n0 = blockIdx.x * 64, k0 = blockIdx.y * 64;
    const int tid = threadIdx.x;
    const int nl = tid & 63, kg = tid >> 6;
#pragma unroll
    for (int i = 0; i < 16; ++i) {
        const int kl = kg * 16 + i;
        T[kl][nl] = W[(size_t)(k0 + kl) * Nd + n0 + nl];
    }
    __syncthreads();
    const int kl = tid & 63;
#pragma unroll
    for (int i = 0; i < 16; ++i) {
        const int nl2 = kg * 16 + i;
        WT[(size_t)(n0 + nl2) * Kd + k0 + kl] = (_Float16)T[kl][nl2];
    }
}

__global__ void catbias(const float* __restrict__ a, const float* __restrict__ b,
                        float* __restrict__ o) {
    const int i = threadIdx.x;  // 512 threads
    o[i] = (i < 256) ? a[i] : b[i - 256];
}

// ---------------------------------------------------------------------------
// GEMM: C(MxN) = A(MxK) @ BT(NxK)^T + bias.  A,BT fp16 [row][k].
// 32x32x16 MFMA. Block 256m x 128n, 4 waves (wm=w>>1, wn=w&1), wave 128x64
// (4 m-tiles x 2 n-tiles of 32). BK=64, single LDS buffer, swizzled
// global_load_lds (16B) staging.
//   EPI 0: Q-proj  (bias+RoPE+*0.125 -> fp16 q_h[b][h][lq][hd]),  N=1024
//   EPI 1: KV-proj (n<256: K bias+RoPE -> k_h[b][kvh][lkv][hd];
//                   n>=256: V bias -> v_t[b][kvh][hd][lkv]),      N=512
//   EPI 2: O-proj  (bias -> fp32 out row-major),                  N=1024
// ---------------------------------------------------------------------------
template <int EPI>
__global__ __launch_bounds__(256, 2) void gemm32(const _Float16* __restrict__ A,
                                                 const _Float16* __restrict__ BT,
                                                 const float* __restrict__ bias,
                                                 void* __restrict__ Cp,
                                                 const int* __restrict__ nfp) {
    constexpr int K = 1024;
    __shared__ _Float16 As[256 * 64];
    __shared__ _Float16 Bs[128 * 64];

    const int tid = threadIdx.x;
    const int lane = tid & 63, l31 = lane & 31, hh = lane >> 5;
    const int w = tid >> 6, wm = w >> 1, wn = w & 1;
    const int n0 = blockIdx.x * 128;
    const int m0 = blockIdx.y * 256;

    f32x16 acc[4][2];
#pragma unroll
    for (int mt = 0; mt < 4; ++mt)
#pragma unroll
        for (int nt = 0; nt < 2; ++nt)
#pragma unroll
            for (int v = 0; v < 16; ++v) acc[mt][nt][v] = 0.f;

    for (int k0 = 0; k0 < K; k0 += 64) {
        // stage A (256 rows x 64 k): 2048 16B-chunks, 8 per thread
#pragma unroll
        for (int i = 0; i < 8; ++i) {
            const int id = i * 256 + tid;
            const int r = id >> 3;
            const int c = (id & 7) ^ (r & 7);  // source-swizzled
            async_cp16(A + (size_t)(m0 + r) * K + k0 + c * 8,
                       As + i * 2048 + w * 512);
        }
        // stage B (128 rows x 64 k): 1024 chunks, 4 per thread
#pragma unroll
        for (int i = 0; i < 4; ++i) {
            const int id = i * 256 + tid;
            const int r = id >> 3;
            const int c = (id & 7) ^ (r & 7);
            async_cp16(BT + (size_t)(n0 + r) * K + k0 + c * 8,
                       Bs + i * 2048 + w * 512);
        }
        __syncthreads();

#pragma unroll
        for (int kk = 0; kk < 4; ++kk) {
            f16x8 af[4], bf[2];
#pragma unroll
            for (int mt = 0; mt < 4; ++mt) {
                const int row = wm * 128 + mt * 32 + l31;
                const int pc = (kk * 2 + hh) ^ (row & 7);
                af[mt] = *(const f16x8*)&As[row * 64 + pc * 8];
            }
#pragma unroll
            for (int nt = 0; nt < 2; ++nt) {
                const int row = wn * 64 + nt * 32 + l31;
                const int pc = (kk * 2 + hh) ^ (row & 7);
                bf[nt] = *(const f16x8*)&Bs[row * 64 + pc * 8];
            }
#pragma unroll
            for (int mt = 0; mt < 4; ++mt)
#pragma unroll
                for (int nt = 0; nt < 2; ++nt)
                    acc[mt][nt] = MFMA32(af[mt], bf[nt], acc[mt][nt]);
        }
        __syncthreads();
    }

    // ---- epilogue.  C/D 32x32 layout: col = l31, row = (v&3)+8*(v>>2)+4*hh
    const int nf = nfp[0];
    const int nbase = n0 + wn * 64;  // wave-uniform, 64-aligned

    // bias
    float bb[2];
#pragma unroll
    for (int nt = 0; nt < 2; ++nt) bb[nt] = bias[nbase + nt * 32 + l31];
#pragma unroll
    for (int mt = 0; mt < 4; ++mt)
#pragma unroll
        for (int nt = 0; nt < 2; ++nt)
#pragma unroll
            for (int v = 0; v < 16; ++v) acc[mt][nt][v] += bb[nt];

    if constexpr (EPI == 0) {  // ---- Q
        const float l2b = 13.287712379549449f;  // log2(10000)
        const float inv = exp2f(-((float)l31 * (1.0f / 32.0f)) * l2b);
        const int dv = 4096 / (nf > 1 ? nf : 1);
        _Float16* O = (_Float16*)Cp;
        const int head = nbase >> 6;
#pragma unroll
        for (int mt = 0; mt < 4; ++mt) {
#pragma unroll
            for (int v = 0; v < 16; ++v) {
                const int m = m0 + wm * 128 + mt * 32 + (v & 3) + 8 * (v >> 2) + 4 * hh;
                const int b = m >> 12, lq = m & 4095;
                if (nf > 1) {
                    const int pos = lq / dv;
                    float s, c;
                    __sincosf((float)pos * inv, &s, &c);
                    const float x1 = acc[mt][0][v], x2 = acc[mt][1][v];
                    acc[mt][0][v] = x1 * c - x2 * s;
                    acc[mt][1][v] = x2 * c + x1 * s;
                }
#pragma unroll
                for (int nt = 0; nt < 2; ++nt) {
                    const int hd = nt * 32 + l31;
                    O[(((size_t)(b * 16 + head)) * 4096 + lq) * 64 + hd] =
                        (_Float16)(acc[mt][nt][v] * 0.125f);
                }
            }
        }
    } else if constexpr (EPI == 1) {  // ---- K / V (N=512 fused)
        _Float16* kout = (_Float16*)Cp;                  // k_h: 4*4*256*64
        _Float16* vout = kout + (size_t)4 * 4 * 256 * 64;  // v_t right after
        if (nbase < 256) {
            const float l2b = 13.287712379549449f;
            const float inv = exp2f(-((float)l31 * (1.0f / 32.0f)) * l2b);
            const int dv = 256 / (nf > 1 ? nf : 1);
            const int kvh = nbase >> 6;
#pragma unroll
            for (int mt = 0; mt < 4; ++mt) {
#pragma unroll
                for (int v = 0; v < 16; ++v) {
                    const int m = m0 + wm * 128 + mt * 32 + (v & 3) + 8 * (v >> 2) + 4 * hh;
                    const int b = m >> 8, lkv = m & 255;
                    if (nf > 1) {
                        const int pos = lkv / dv;
                        float s, c;
                        __sincosf((float)pos * inv, &s, &c);
                        const float x1 = acc[mt][0][v], x2 = acc[mt][1][v];
                        acc[mt][0][v] = x1 * c - x2 * s;
                        acc[mt][1][v] = x2 * c + x1 * s;
                    }
#pragma unroll
                    for (int nt = 0; nt < 2; ++nt) {
                        const int hd = nt * 32 + l31;
                        kout[(((size_t)(b * 4 + kvh)) * 256 + lkv) * 64 + hd] =
                            (_Float16)acc[mt][nt][v];
                    }
                }
            }
        } else {
            const int kvh = (nbase - 256) >> 6;
#pragma unroll
            for (int mt = 0; mt < 4; ++mt) {
#pragma unroll
                for (int v = 0; v < 16; ++v) {
                    const int m = m0 + wm * 128 + mt * 32 + (v & 3) + 8 * (v >> 2) + 4 * hh;
                    const int b = m >> 8, lkv = m & 255;
#pragma unroll
                    for (int nt = 0; nt < 2; ++nt) {
                        const int hd = nt * 32 + l31;
                        vout[(((size_t)(b * 4 + kvh)) * 64 + hd) * 256 + lkv] =
                            (_Float16)acc[mt][nt][v];
                    }
                }
            }
        }
    } else {  // ---- O-proj, fp32 row-major
        float* O = (float*)Cp;
#pragma unroll
        for (int mt = 0; mt < 4; ++mt) {
#pragma unroll
            for (int v = 0; v < 16; ++v) {
                const int m = m0 + wm * 128 + mt * 32 + (v & 3) + 8 * (v >> 2) + 4 * hh;
#pragma unroll
                for (int nt = 0; nt < 2; ++nt)
                    O[(size_t)m * 1024 + nbase + nt * 32 + l31] = acc[mt][nt][v];
            }
        }
    }
}

// ---------------------------------------------------------------------------
// Attention v2. Block = 4 waves = 256 q-rows of one (b,h); wave = 64 rows,
// 2 super-iters x 2 m-tiles(16). S^T = K @ Q^T trick: Q B-frag == Q A-frag
// data; softmax rows on l15 -> 2 shuffles; P stored as contiguous b64.
// K/V/Q from global (L2-hot); only P round-trips through per-wave LDS.
// ---------------------------------------------------------------------------
__global__ __launch_bounds__(256, 2) void attn2(const _Float16* __restrict__ qh,
                                                const _Float16* __restrict__ kh,
                                                const _Float16* __restrict__ vt,
                                                _Float16* __restrict__ attn) {
    __shared__ _Float16 Ps[4][16][264];  // per-wave P: 16 q-rows x 256 kv (+8)

    const int tid = threadIdx.x;
    const int w = tid >> 6, lane = tid & 63, quad = lane >> 4, l15 = lane & 15;
    const int bh = blockIdx.y, b = bh >> 4, h = bh & 15, kvh = h >> 2;
    const int q0 = blockIdx.x * 256;

    const _Float16* kb = kh + (size_t)(b * 4 + kvh) * 256 * 64;
    const _Float16* vb = vt + (size_t)(b * 4 + kvh) * 64 * 256;
    const _Float16* qb = qh + (size_t)bh * 4096 * 64;

#pragma unroll
    for (int si = 0; si < 2; ++si) {
        const int qw = q0 + w * 64 + si * 32;

        // Q fragments (scale 1/8 folded in at Q-proj). B-frag == A-frag data.
        f16x8 bq[2][2];
#pragma unroll
        for (int mt = 0; mt < 2; ++mt)
#pragma unroll
            for (int hv = 0; hv < 2; ++hv)
                bq[mt][hv] = *(const f16x8*)(qb + (size_t)(qw + mt * 16 + l15) * 64 +
                                             hv * 32 + quad * 8);

        // S^T = K @ Q^T : C-frag holds S[q=l15][kv=t*16+quad*4+rr]
        f32x4 st[2][16];
#pragma unroll
        for (int mt = 0; mt < 2; ++mt)
#pragma unroll
            for (int t = 0; t < 16; ++t)
#pragma unroll
                for (int rr = 0; rr < 4; ++rr) st[mt][t][rr] = 0.f;

#pragma unroll
        for (int t = 0; t < 16; ++t) {
            const _Float16* kp = kb + (size_t)(t * 16 + l15) * 64 + quad * 8;
            const f16x8 ka0 = *(const f16x8*)kp;
            const f16x8 ka1 = *(const f16x8*)(kp + 32);
            st[0][t] = MFMA16(ka0, bq[0][0], st[0][t]);
            st[0][t] = MFMA16(ka1, bq[0][1], st[0][t]);
            st[1][t] = MFMA16(ka0, bq[1][0], st[1][t]);
            st[1][t] = MFMA16(ka1, bq[1][1], st[1][t]);
        }

        // per m-tile: softmax -> P to LDS -> PV -> store (Ps reused across mt)
#pragma unroll
        for (int mt = 0; mt < 2; ++mt) {
            float rm = -1e30f;
#pragma unroll
            for (int t = 0; t < 16; ++t)
#pragma unroll
                for (int rr = 0; rr < 4; ++rr) rm = fmaxf(rm, st[mt][t][rr]);
            rm = fmaxf(rm, __shfl_xor(rm, 16, 64));
            rm = fmaxf(rm, __shfl_xor(rm, 32, 64));

            float rs = 0.f;
#pragma unroll
            for (int t = 0; t < 16; ++t) {
                const float p0 = __expf(st[mt][t][0] - rm);
                const float p1 = __expf(st[mt][t][1] - rm);
                const float p2 = __expf(st[mt][t][2] - rm);
                const float p3 = __expf(st[mt][t][3] - rm);
                rs += (p0 + p1) + (p2 + p3);
                f16x4 pk;
                pk[0] = (_Float16)p0; pk[1] = (_Float16)p1;
                pk[2] = (_Float16)p2; pk[3] = (_Float16)p3;
                *(f16x4*)&Ps[w][l15][t * 16 + quad * 4] = pk;  // b64, contiguous kv
            }
            rs += __shfl_xor(rs, 16, 64);
            rs += __shfl_xor(rs, 32, 64);
            const float ir = 1.0f / rs;  // inv-sum for row q=l15

            // O = P @ V (A=P from LDS, B=Vt rows from global)
            f32x4 o[4];
#pragma unroll
            for (int nt = 0; nt < 4; ++nt)
#pragma unroll
                for (int rr = 0; rr < 4; ++rr) o[nt][rr] = 0.f;
#pragma unroll
            for (int kk = 0; kk < 8; ++kk) {
                const f16x8 pa = *(const f16x8*)&Ps[w][l15][kk * 32 + quad * 8];
#pragma unroll
                for (int nt = 0; nt < 4; ++nt) {
                    const f16x8 bv = *(const f16x8*)(vb + (size_t)(nt * 16 + l15) * 256 +
                                                     kk * 32 + quad * 8);
                    o[nt] = MFMA16(pa, bv, o[nt]);
                }
            }

            // rows of O C-frag are q = quad*4+rr; fetch that row's inv-sum
#pragma unroll
            for (int rr = 0; rr < 4; ++rr) {
                const float irr = __shfl(ir, quad * 4 + rr, 64);
                const int row = qw + mt * 16 + quad * 4 + rr;
#pragma unroll
                for (int nt = 0; nt < 4; ++nt) {
                    attn[(((size_t)b * 4096) + row) * 1024 + h * 64 + nt * 16 + l15] =
                        (_Float16)(o[nt][rr] * irr);
                }
            }
        }
    }
}

// ---------------------------------------------------------------------------
extern "C" void kernel_launch(void* const* d_in, const int* in_sizes, int n_in,
                              void* d_out, int out_size, void* d_ws, size_t ws_size,
                              hipStream_t stream) {
    const float* patches = (const float*)d_in[0];
    const float* latents = (const float*)d_in[1];
    const float* Wq = (const float*)d_in[2];
    const float* bq = (const float*)d_in[3];
    const float* Wk = (const float*)d_in[4];
    const float* bk = (const float*)d_in[5];
    const float* Wv = (const float*)d_in[6];
    const float* bv = (const float*)d_in[7];
    const float* Wo = (const float*)d_in[8];
    const float* bo = (const float*)d_in[9];
    const int*   nf = (const int*)d_in[10];
    float* out = (float*)d_out;
    (void)in_sizes; (void)n_in; (void)out_size; (void)ws_size;

    char* p = (char*)d_ws;
    _Float16* WqT  = (_Float16*)p; p += (size_t)1024 * 1024 * 2;
    _Float16* WkvT = (_Float16*)p; p += (size_t)512 * 1024 * 2;
    _Float16* WoT  = (_Float16*)p; p += (size_t)1024 * 1024 * 2;
    float*    bkv  = (float*)p;    p += 4096;
    _Float16* p16  = (_Float16*)p; p += (size_t)4 * 4096 * 1024 * 2;
    _Float16* l16  = (_Float16*)p; p += (size_t)4 * 256 * 1024 * 2;
    _Float16* q_h  = (_Float16*)p; p += (size_t)4 * 16 * 4096 * 64 * 2;
    _Float16* k_h  = (_Float16*)p; p += (size_t)4 * 4 * 256 * 64 * 2;
    _Float16* v_t  = (_Float16*)p; p += (size_t)4 * 4 * 256 * 64 * 2;  // right after k_h
    _Float16* attn_h = (_Float16*)p; p += (size_t)16384 * 1024 * 2;

    // input converts
    cvt_f16<<<16384, 256, 0, stream>>>((const float4*)patches, (f16x4*)p16);
    cvt_f16<<<1024, 256, 0, stream>>>((const float4*)latents, (f16x4*)l16);

    // weights -> fp16 [n][k] (Wk/Wv concatenated)
    transpose_cvt<<<dim3(16, 16), 256, 0, stream>>>(Wq, WqT, 1024, 1024);
    transpose_cvt<<<dim3(4, 16), 256, 0, stream>>>(Wk, WkvT, 1024, 256);
    transpose_cvt<<<dim3(4, 16), 256, 0, stream>>>(Wv, WkvT + (size_t)256 * 1024, 1024, 256);
    transpose_cvt<<<dim3(16, 16), 256, 0, stream>>>(Wo, WoT, 1024, 1024);
    catbias<<<1, 512, 0, stream>>>(bk, bv, bkv);

    // projections
    gemm32<0><<<dim3(8, 64), 256, 0, stream>>>(p16, WqT, bq, q_h, nf);
    gemm32<1><<<dim3(4, 4), 256, 0, stream>>>(l16, WkvT, bkv, k_h, nf);

    // attention
    attn2<<<dim3(16, 64), 256, 0, stream>>>(q_h, k_h, v_t, attn_h);

    // output projection
    gemm32<2><<<dim3(8, 64), 256, 0, stream>>>(attn_h, WoT, bo, out, nf);
}

// Round 3
// 365.434 us; speedup vs baseline: 1.3088x; 1.0388x over previous
//
#include <hip/hip_runtime.h>
#include <hip/hip_fp16.h>
#include <cstdint>

typedef _Float16 f16x8 __attribute__((ext_vector_type(8)));
typedef _Float16 f16x4 __attribute__((ext_vector_type(4)));
typedef float    f32x4 __attribute__((ext_vector_type(4)));
typedef float    f32x16 __attribute__((ext_vector_type(16)));

#define MFMA16(a, b, c) __builtin_amdgcn_mfma_f32_16x16x32_f16((a), (b), (c), 0, 0, 0)
#define MFMA32(a, b, c) __builtin_amdgcn_mfma_f32_32x32x16_f16((a), (b), (c), 0, 0, 0)

// B=4, LQ=4096, LKV=256, D=1024, H=16, KVH=4, HD=64

__device__ __forceinline__ void async_cp16(const _Float16* g, _Float16* l) {
    __builtin_amdgcn_global_load_lds(
        (const __attribute__((address_space(1))) void*)g,
        (__attribute__((address_space(3))) void*)l, 16, 0, 0);
}

// ---------------------------------------------------------------------------
// fp32 -> fp16 convert for patches + latents in one launch
// ---------------------------------------------------------------------------
__global__ __launch_bounds__(256) void cvt_all(const float4* __restrict__ patches,
                                               const float4* __restrict__ latents,
                                               f16x4* __restrict__ p16,
                                               f16x4* __restrict__ l16) {
    const long i = (long)blockIdx.x * 256 + threadIdx.x;
    const float4 v = (i < 4194304) ? patches[i] : latents[i - 4194304];
    f16x4 o;
    o[0] = (_Float16)v.x; o[1] = (_Float16)v.y;
    o[2] = (_Float16)v.z; o[3] = (_Float16)v.w;
    if (i < 4194304) p16[i] = o; else l16[i - 4194304] = o;
}

// ---------------------------------------------------------------------------
// All 4 weight transposes (fp32 [K][N] -> fp16 [N][K]) in one launch.
// ---------------------------------------------------------------------------
__global__ __launch_bounds__(256) void transpose_all(
    const float* __restrict__ Wq, const float* __restrict__ Wk,
    const float* __restrict__ Wv, const float* __restrict__ Wo,
    _Float16* __restrict__ WqT, _Float16* __restrict__ WkvT,
    _Float16* __restrict__ WoT) {
    const int z = blockIdx.z;
    const float* W;
    _Float16* WT;
    int Nd;
    if (z == 0)      { W = Wq; WT = WqT;                       Nd = 1024; }
    else if (z == 1) { W = Wk; WT = WkvT;                      Nd = 256;  }
    else if (z == 2) { W = Wv; WT = WkvT + (size_t)256 * 1024; Nd = 256;  }
    else             { W = Wo; WT = WoT;                       Nd = 1024; }
    const int n0 = blockIdx.x * 64, k0 = blockIdx.y * 64;
    if (n0 >= Nd) return;

    __shared__ float T[64][65];
    const int tid = threadIdx.x;
    const int nl = tid & 63, kg = tid >> 6;
#pragma unroll
    for (int i = 0; i < 16; ++i) {
        const int kl = kg * 16 + i;
        T[kl][nl] = W[(size_t)(k0 + kl) * Nd + n0 + nl];
    }
    __syncthreads();
    const int kl = tid & 63;
#pragma unroll
    for (int i = 0; i < 16; ++i) {
        const int nl2 = kg * 16 + i;
        WT[(size_t)(n0 + nl2) * 1024 + k0 + kl] = (_Float16)T[kl][nl2];
    }
}

__global__ void catbias(const float* __restrict__ a, const float* __restrict__ b,
                        float* __restrict__ o) {
    const int i = threadIdx.x;  // 512 threads
    o[i] = (i < 256) ? a[i] : b[i - 256];
}

// ---------------------------------------------------------------------------
// GEMM: C(MxN) = A(MxK) @ BT(NxK)^T + bias.  A,BT fp16 [row][k].
// 32x32x16 MFMA. Block 256m x 128n, 4 waves, wave 128x64. BK=64, swizzled
// global_load_lds staging.  (unchanged from round 2)
// ---------------------------------------------------------------------------
template <int EPI>
__global__ __launch_bounds__(256, 2) void gemm32(const _Float16* __restrict__ A,
                                                 const _Float16* __restrict__ BT,
                                                 const float* __restrict__ bias,
                                                 void* __restrict__ Cp,
                                                 const int* __restrict__ nfp) {
    constexpr int K = 1024;
    __shared__ _Float16 As[256 * 64];
    __shared__ _Float16 Bs[128 * 64];

    const int tid = threadIdx.x;
    const int lane = tid & 63, l31 = lane & 31, hh = lane >> 5;
    const int w = tid >> 6, wm = w >> 1, wn = w & 1;
    const int n0 = blockIdx.x * 128;
    const int m0 = blockIdx.y * 256;

    f32x16 acc[4][2];
#pragma unroll
    for (int mt = 0; mt < 4; ++mt)
#pragma unroll
        for (int nt = 0; nt < 2; ++nt)
#pragma unroll
            for (int v = 0; v < 16; ++v) acc[mt][nt][v] = 0.f;

    for (int k0 = 0; k0 < K; k0 += 64) {
#pragma unroll
        for (int i = 0; i < 8; ++i) {
            const int id = i * 256 + tid;
            const int r = id >> 3;
            const int c = (id & 7) ^ (r & 7);
            async_cp16(A + (size_t)(m0 + r) * K + k0 + c * 8,
                       As + i * 2048 + w * 512);
        }
#pragma unroll
        for (int i = 0; i < 4; ++i) {
            const int id = i * 256 + tid;
            const int r = id >> 3;
            const int c = (id & 7) ^ (r & 7);
            async_cp16(BT + (size_t)(n0 + r) * K + k0 + c * 8,
                       Bs + i * 2048 + w * 512);
        }
        __syncthreads();

#pragma unroll
        for (int kk = 0; kk < 4; ++kk) {
            f16x8 af[4], bf[2];
#pragma unroll
            for (int mt = 0; mt < 4; ++mt) {
                const int row = wm * 128 + mt * 32 + l31;
                const int pc = (kk * 2 + hh) ^ (row & 7);
                af[mt] = *(const f16x8*)&As[row * 64 + pc * 8];
            }
#pragma unroll
            for (int nt = 0; nt < 2; ++nt) {
                const int row = wn * 64 + nt * 32 + l31;
                const int pc = (kk * 2 + hh) ^ (row & 7);
                bf[nt] = *(const f16x8*)&Bs[row * 64 + pc * 8];
            }
#pragma unroll
            for (int mt = 0; mt < 4; ++mt)
#pragma unroll
                for (int nt = 0; nt < 2; ++nt)
                    acc[mt][nt] = MFMA32(af[mt], bf[nt], acc[mt][nt]);
        }
        __syncthreads();
    }

    const int nf = nfp[0];
    const int nbase = n0 + wn * 64;

    float bb[2];
#pragma unroll
    for (int nt = 0; nt < 2; ++nt) bb[nt] = bias[nbase + nt * 32 + l31];
#pragma unroll
    for (int mt = 0; mt < 4; ++mt)
#pragma unroll
        for (int nt = 0; nt < 2; ++nt)
#pragma unroll
            for (int v = 0; v < 16; ++v) acc[mt][nt][v] += bb[nt];

    if constexpr (EPI == 0) {  // Q: bias+RoPE+0.125 -> q_h[b][h][lq][hd]
        const float l2b = 13.287712379549449f;
        const float inv = exp2f(-((float)l31 * (1.0f / 32.0f)) * l2b);
        const int dv = 4096 / (nf > 1 ? nf : 1);
        _Float16* O = (_Float16*)Cp;
        const int head = nbase >> 6;
#pragma unroll
        for (int mt = 0; mt < 4; ++mt) {
#pragma unroll
            for (int v = 0; v < 16; ++v) {
                const int m = m0 + wm * 128 + mt * 32 + (v & 3) + 8 * (v >> 2) + 4 * hh;
                const int b = m >> 12, lq = m & 4095;
                if (nf > 1) {
                    const int pos = lq / dv;
                    float s, c;
                    __sincosf((float)pos * inv, &s, &c);
                    const float x1 = acc[mt][0][v], x2 = acc[mt][1][v];
                    acc[mt][0][v] = x1 * c - x2 * s;
                    acc[mt][1][v] = x2 * c + x1 * s;
                }
#pragma unroll
                for (int nt = 0; nt < 2; ++nt) {
                    const int hd = nt * 32 + l31;
                    O[(((size_t)(b * 16 + head)) * 4096 + lq) * 64 + hd] =
                        (_Float16)(acc[mt][nt][v] * 0.125f);
                }
            }
        }
    } else if constexpr (EPI == 1) {  // K/V fused (N=512)
        _Float16* kout = (_Float16*)Cp;
        _Float16* vout = kout + (size_t)4 * 4 * 256 * 64;
        if (nbase < 256) {
            const float l2b = 13.287712379549449f;
            const float inv = exp2f(-((float)l31 * (1.0f / 32.0f)) * l2b);
            const int dv = 256 / (nf > 1 ? nf : 1);
            const int kvh = nbase >> 6;
#pragma unroll
            for (int mt = 0; mt < 4; ++mt) {
#pragma unroll
                for (int v = 0; v < 16; ++v) {
                    const int m = m0 + wm * 128 + mt * 32 + (v & 3) + 8 * (v >> 2) + 4 * hh;
                    const int b = m >> 8, lkv = m & 255;
                    if (nf > 1) {
                        const int pos = lkv / dv;
                        float s, c;
                        __sincosf((float)pos * inv, &s, &c);
                        const float x1 = acc[mt][0][v], x2 = acc[mt][1][v];
                        acc[mt][0][v] = x1 * c - x2 * s;
                        acc[mt][1][v] = x2 * c + x1 * s;
                    }
#pragma unroll
                    for (int nt = 0; nt < 2; ++nt) {
                        const int hd = nt * 32 + l31;
                        kout[(((size_t)(b * 4 + kvh)) * 256 + lkv) * 64 + hd] =
                            (_Float16)acc[mt][nt][v];
                    }
                }
            }
        } else {
            const int kvh = (nbase - 256) >> 6;
#pragma unroll
            for (int mt = 0; mt < 4; ++mt) {
#pragma unroll
                for (int v = 0; v < 16; ++v) {
                    const int m = m0 + wm * 128 + mt * 32 + (v & 3) + 8 * (v >> 2) + 4 * hh;
                    const int b = m >> 8, lkv = m & 255;
#pragma unroll
                    for (int nt = 0; nt < 2; ++nt) {
                        const int hd = nt * 32 + l31;
                        vout[(((size_t)(b * 4 + kvh)) * 64 + hd) * 256 + lkv] =
                            (_Float16)acc[mt][nt][v];
                    }
                }
            }
        }
    } else {  // O-proj fp32
        float* O = (float*)Cp;
#pragma unroll
        for (int mt = 0; mt < 4; ++mt) {
#pragma unroll
            for (int v = 0; v < 16; ++v) {
                const int m = m0 + wm * 128 + mt * 32 + (v & 3) + 8 * (v >> 2) + 4 * hh;
#pragma unroll
                for (int nt = 0; nt < 2; ++nt)
                    O[(size_t)m * 1024 + nbase + nt * 32 + l31] = acc[mt][nt][v];
            }
        }
    }
}

// ---------------------------------------------------------------------------
// Attention v3.  Block = 4 waves = 256 q-rows of one (b,h).
//  - K (256x64) staged once into LDS (swizzled) via global_load_lds.
//  - V^T (64x256) loaded once per wave into 128 VGPRs (L2-hot), so the PV
//    loop has no memory ops except the P round-trip.
//  - Each wave: 4 chunks of 16 q-rows.  S^T = K @ Q^T (64-reg acc), 2-shuffle
//    softmax, P -> per-wave padded LDS (2-way banks), PV from regs.
// ---------------------------------------------------------------------------
__global__ __launch_bounds__(256, 2) void attn3(const _Float16* __restrict__ qh,
                                                const _Float16* __restrict__ kh,
                                                const _Float16* __restrict__ vt,
                                                _Float16* __restrict__ attn) {
    __shared__ _Float16 Ks[256 * 64];    // swizzled: chunk c of row r at c^(r&7)
    __shared__ _Float16 Ps[4][16 * 264]; // per-wave P, pad 8

    const int tid = threadIdx.x;
    const int w = tid >> 6, lane = tid & 63, quad = lane >> 4, l15 = lane & 15;
    const int bh = blockIdx.y, b = bh >> 4, h = bh & 15, kvh = h >> 2;
    const int q0 = blockIdx.x * 256;

    const _Float16* kb = kh + (size_t)(b * 4 + kvh) * 256 * 64;
    const _Float16* vb = vt + (size_t)(b * 4 + kvh) * 64 * 256;
    const _Float16* qb = qh + ((size_t)bh * 4096 + q0) * 64;

    // ---- stage K into LDS (2048 x 16B chunks, 8/thread), source-swizzled
#pragma unroll
    for (int i = 0; i < 8; ++i) {
        const int id = i * 256 + tid;
        const int r = id >> 3;
        const int c = (id & 7) ^ (r & 7);
        async_cp16(kb + (size_t)r * 64 + c * 8, Ks + i * 2048 + w * 512);
    }

    // ---- V^T into registers: B-frag [hd = nt*16+l15][kv = kk*32+quad*8]
    f16x8 vf[8][4];
#pragma unroll
    for (int kk = 0; kk < 8; ++kk)
#pragma unroll
        for (int nt = 0; nt < 4; ++nt)
            vf[kk][nt] = *(const f16x8*)(vb + (size_t)(nt * 16 + l15) * 256 +
                                         kk * 32 + quad * 8);

    __syncthreads();  // K staged

    const int sw = (l15 & 7);  // read-side swizzle key
    _Float16* Pw = &Ps[w][0];

#pragma unroll 1
    for (int chunk = 0; chunk < 4; ++chunk) {
        const int qrow = w * 64 + chunk * 16;

        // Q B-frags (scale 1/8 folded in at Q-proj)
        const _Float16* qp = qb + (size_t)(qrow + l15) * 64 + quad * 8;
        const f16x8 bq0 = *(const f16x8*)qp;
        const f16x8 bq1 = *(const f16x8*)(qp + 32);

        // S^T = K @ Q^T : lane holds S[q=l15][kv=t*16+quad*4+rr]
        f32x4 st[16];
#pragma unroll
        for (int t = 0; t < 16; ++t)
#pragma unroll
            for (int rr = 0; rr < 4; ++rr) st[t][rr] = 0.f;

#pragma unroll
        for (int t = 0; t < 16; ++t) {
            const int row = t * 16 + l15;
            const int p0 = quad ^ sw;       // logical chunk quad   (k 0..31)
            const f16x8 ka0 = *(const f16x8*)&Ks[row * 64 + p0 * 8];
            const f16x8 ka1 = *(const f16x8*)&Ks[row * 64 + (p0 ^ 4) * 8];
            st[t] = MFMA16(ka0, bq0, st[t]);
            st[t] = MFMA16(ka1, bq1, st[t]);
        }

        // softmax over 256 kv (rows on l15 -> 2 shuffles)
        float rm = -1e30f;
#pragma unroll
        for (int t = 0; t < 16; ++t)
#pragma unroll
            for (int rr = 0; rr < 4; ++rr) rm = fmaxf(rm, st[t][rr]);
        rm = fmaxf(rm, __shfl_xor(rm, 16, 64));
        rm = fmaxf(rm, __shfl_xor(rm, 32, 64));

        float rs = 0.f;
#pragma unroll
        for (int t = 0; t < 16; ++t) {
            const float p0 = __expf(st[t][0] - rm);
            const float p1 = __expf(st[t][1] - rm);
            const float p2 = __expf(st[t][2] - rm);
            const float p3 = __expf(st[t][3] - rm);
            rs += (p0 + p1) + (p2 + p3);
            f16x4 pk;
            pk[0] = (_Float16)p0; pk[1] = (_Float16)p1;
            pk[2] = (_Float16)p2; pk[3] = (_Float16)p3;
            *(f16x4*)&Pw[l15 * 264 + t * 16 + quad * 4] = pk;
        }
        rs += __shfl_xor(rs, 16, 64);
        rs += __shfl_xor(rs, 32, 64);
        const float ir = 1.0f / rs;

        // O = P @ V (V in regs)
        f32x4 o[4];
#pragma unroll
        for (int nt = 0; nt < 4; ++nt)
#pragma unroll
            for (int rr = 0; rr < 4; ++rr) o[nt][rr] = 0.f;
#pragma unroll
        for (int kk = 0; kk < 8; ++kk) {
            const f16x8 pa = *(const f16x8*)&Pw[l15 * 264 + kk * 32 + quad * 8];
#pragma unroll
            for (int nt = 0; nt < 4; ++nt) o[nt] = MFMA16(pa, vf[kk][nt], o[nt]);
        }

        // store (C rows are q = quad*4+rr)
#pragma unroll
        for (int rr = 0; rr < 4; ++rr) {
            const float irr = __shfl(ir, quad * 4 + rr, 64);
            const int row = q0 + qrow + quad * 4 + rr;
#pragma unroll
            for (int nt = 0; nt < 4; ++nt) {
                attn[(((size_t)b * 4096) + row) * 1024 + h * 64 + nt * 16 + l15] =
                    (_Float16)(o[nt][rr] * irr);
            }
        }
    }
}

// ---------------------------------------------------------------------------
extern "C" void kernel_launch(void* const* d_in, const int* in_sizes, int n_in,
                              void* d_out, int out_size, void* d_ws, size_t ws_size,
                              hipStream_t stream) {
    const float* patches = (const float*)d_in[0];
    const float* latents = (const float*)d_in[1];
    const float* Wq = (const float*)d_in[2];
    const float* bq = (const float*)d_in[3];
    const float* Wk = (const float*)d_in[4];
    const float* bk = (const float*)d_in[5];
    const float* Wv = (const float*)d_in[6];
    const float* bv = (const float*)d_in[7];
    const float* Wo = (const float*)d_in[8];
    const float* bo = (const float*)d_in[9];
    const int*   nf = (const int*)d_in[10];
    float* out = (float*)d_out;
    (void)in_sizes; (void)n_in; (void)out_size; (void)ws_size;

    char* p = (char*)d_ws;
    _Float16* WqT  = (_Float16*)p; p += (size_t)1024 * 1024 * 2;
    _Float16* WkvT = (_Float16*)p; p += (size_t)512 * 1024 * 2;
    _Float16* WoT  = (_Float16*)p; p += (size_t)1024 * 1024 * 2;
    float*    bkv  = (float*)p;    p += 4096;
    _Float16* p16  = (_Float16*)p; p += (size_t)4 * 4096 * 1024 * 2;
    _Float16* l16  = (_Float16*)p; p += (size_t)4 * 256 * 1024 * 2;
    _Float16* q_h  = (_Float16*)p; p += (size_t)4 * 16 * 4096 * 64 * 2;
    _Float16* k_h  = (_Float16*)p; p += (size_t)4 * 4 * 256 * 64 * 2;
    _Float16* v_t  = (_Float16*)p; p += (size_t)4 * 4 * 256 * 64 * 2;  // after k_h
    _Float16* attn_h = (_Float16*)p; p += (size_t)16384 * 1024 * 2;

    cvt_all<<<17408, 256, 0, stream>>>((const float4*)patches, (const float4*)latents,
                                       (f16x4*)p16, (f16x4*)l16);
    transpose_all<<<dim3(16, 16, 4), 256, 0, stream>>>(Wq, Wk, Wv, Wo, WqT, WkvT, WoT);
    catbias<<<1, 512, 0, stream>>>(bk, bv, bkv);

    gemm32<1><<<dim3(4, 4), 256, 0, stream>>>(l16, WkvT, bkv, k_h, nf);
    gemm32<0><<<dim3(8, 64), 256, 0, stream>>>(p16, WqT, bq, q_h, nf);

    attn3<<<dim3(16, 64), 256, 0, stream>>>(q_h, k_h, v_t, attn_h);

    gemm32<2><<<dim3(8, 64), 256, 0, stream>>>(attn_h, WoT, bo, out, nf);
}

// Round 4
// 359.310 us; speedup vs baseline: 1.3311x; 1.0170x over previous
//
#include <hip/hip_runtime.h>
#include <hip/hip_fp16.h>
#include <cstdint>

typedef _Float16 f16x8 __attribute__((ext_vector_type(8)));
typedef _Float16 f16x4 __attribute__((ext_vector_type(4)));
typedef float    f32x4 __attribute__((ext_vector_type(4)));
typedef float    f32x16 __attribute__((ext_vector_type(16)));

#define MFMA16(a, b, c) __builtin_amdgcn_mfma_f32_16x16x32_f16((a), (b), (c), 0, 0, 0)
#define MFMA32(a, b, c) __builtin_amdgcn_mfma_f32_32x32x16_f16((a), (b), (c), 0, 0, 0)

// B=4, LQ=4096, LKV=256, D=1024, H=16, KVH=4, HD=64

__device__ __forceinline__ void async_cp16(const _Float16* g, _Float16* l) {
    __builtin_amdgcn_global_load_lds(
        (const __attribute__((address_space(1))) void*)g,
        (__attribute__((address_space(3))) void*)l, 16, 0, 0);
}

// ---------------------------------------------------------------------------
// fp32 -> fp16 convert for patches + latents in one launch
// ---------------------------------------------------------------------------
__global__ __launch_bounds__(256) void cvt_all(const float4* __restrict__ patches,
                                               const float4* __restrict__ latents,
                                               f16x4* __restrict__ p16,
                                               f16x4* __restrict__ l16) {
    const long i = (long)blockIdx.x * 256 + threadIdx.x;
    const float4 v = (i < 4194304) ? patches[i] : latents[i - 4194304];
    f16x4 o;
    o[0] = (_Float16)v.x; o[1] = (_Float16)v.y;
    o[2] = (_Float16)v.z; o[3] = (_Float16)v.w;
    if (i < 4194304) p16[i] = o; else l16[i - 4194304] = o;
}

// ---------------------------------------------------------------------------
// All 4 weight transposes (fp32 [K][N] -> fp16 [N][K]) in one launch.
// ---------------------------------------------------------------------------
__global__ __launch_bounds__(256) void transpose_all(
    const float* __restrict__ Wq, const float* __restrict__ Wk,
    const float* __restrict__ Wv, const float* __restrict__ Wo,
    _Float16* __restrict__ WqT, _Float16* __restrict__ WkvT,
    _Float16* __restrict__ WoT) {
    const int z = blockIdx.z;
    const float* W;
    _Float16* WT;
    int Nd;
    if (z == 0)      { W = Wq; WT = WqT;                       Nd = 1024; }
    else if (z == 1) { W = Wk; WT = WkvT;                      Nd = 256;  }
    else if (z == 2) { W = Wv; WT = WkvT + (size_t)256 * 1024; Nd = 256;  }
    else             { W = Wo; WT = WoT;                       Nd = 1024; }
    const int n0 = blockIdx.x * 64, k0 = blockIdx.y * 64;
    if (n0 >= Nd) return;

    __shared__ float T[64][65];
    const int tid = threadIdx.x;
    const int nl = tid & 63, kg = tid >> 6;
#pragma unroll
    for (int i = 0; i < 16; ++i) {
        const int kl = kg * 16 + i;
        T[kl][nl] = W[(size_t)(k0 + kl) * Nd + n0 + nl];
    }
    __syncthreads();
    const int kl = tid & 63;
#pragma unroll
    for (int i = 0; i < 16; ++i) {
        const int nl2 = kg * 16 + i;
        WT[(size_t)(n0 + nl2) * 1024 + k0 + kl] = (_Float16)T[kl][nl2];
    }
}

__global__ void catbias(const float* __restrict__ a, const float* __restrict__ b,
                        float* __restrict__ o) {
    const int i = threadIdx.x;  // 512 threads
    o[i] = (i < 256) ? a[i] : b[i - 256];
}

// ---------------------------------------------------------------------------
// GEMM: C(MxN) = A(MxK) @ BT(NxK)^T + bias.  A,BT fp16 [row][k].
// 32x32x16 MFMA. Block 256m x 128n, 4 waves, wave 128x64. BK=64, swizzled
// global_load_lds staging.
//   EPI 0: Q-proj  (bias+RoPE+*0.125 -> fp16 q_h[b][h][lq][hd]),  N=1024
//   EPI 1: KV-proj (n<256: K bias+RoPE -> k_h[b][kvh][lkv][hd];
//                   n>=256: V bias -> v_pi[b][kvh][hd][s(lkv)]),  N=512
//   EPI 2: O-proj  (bias -> fp32 out row-major),                  N=1024
// ---------------------------------------------------------------------------
template <int EPI>
__global__ __launch_bounds__(256, 2) void gemm32(const _Float16* __restrict__ A,
                                                 const _Float16* __restrict__ BT,
                                                 const float* __restrict__ bias,
                                                 void* __restrict__ Cp,
                                                 const int* __restrict__ nfp) {
    constexpr int K = 1024;
    __shared__ _Float16 As[256 * 64];
    __shared__ _Float16 Bs[128 * 64];

    const int tid = threadIdx.x;
    const int lane = tid & 63, l31 = lane & 31, hh = lane >> 5;
    const int w = tid >> 6, wm = w >> 1, wn = w & 1;
    const int n0 = blockIdx.x * 128;
    const int m0 = blockIdx.y * 256;

    f32x16 acc[4][2];
#pragma unroll
    for (int mt = 0; mt < 4; ++mt)
#pragma unroll
        for (int nt = 0; nt < 2; ++nt)
#pragma unroll
            for (int v = 0; v < 16; ++v) acc[mt][nt][v] = 0.f;

    for (int k0 = 0; k0 < K; k0 += 64) {
#pragma unroll
        for (int i = 0; i < 8; ++i) {
            const int id = i * 256 + tid;
            const int r = id >> 3;
            const int c = (id & 7) ^ (r & 7);
            async_cp16(A + (size_t)(m0 + r) * K + k0 + c * 8,
                       As + i * 2048 + w * 512);
        }
#pragma unroll
        for (int i = 0; i < 4; ++i) {
            const int id = i * 256 + tid;
            const int r = id >> 3;
            const int c = (id & 7) ^ (r & 7);
            async_cp16(BT + (size_t)(n0 + r) * K + k0 + c * 8,
                       Bs + i * 2048 + w * 512);
        }
        __syncthreads();

#pragma unroll
        for (int kk = 0; kk < 4; ++kk) {
            f16x8 af[4], bf[2];
#pragma unroll
            for (int mt = 0; mt < 4; ++mt) {
                const int row = wm * 128 + mt * 32 + l31;
                const int pc = (kk * 2 + hh) ^ (row & 7);
                af[mt] = *(const f16x8*)&As[row * 64 + pc * 8];
            }
#pragma unroll
            for (int nt = 0; nt < 2; ++nt) {
                const int row = wn * 64 + nt * 32 + l31;
                const int pc = (kk * 2 + hh) ^ (row & 7);
                bf[nt] = *(const f16x8*)&Bs[row * 64 + pc * 8];
            }
#pragma unroll
            for (int mt = 0; mt < 4; ++mt)
#pragma unroll
                for (int nt = 0; nt < 2; ++nt)
                    acc[mt][nt] = MFMA32(af[mt], bf[nt], acc[mt][nt]);
        }
        __syncthreads();
    }

    const int nf = nfp[0];
    const int nbase = n0 + wn * 64;

    float bb[2];
#pragma unroll
    for (int nt = 0; nt < 2; ++nt) bb[nt] = bias[nbase + nt * 32 + l31];
#pragma unroll
    for (int mt = 0; mt < 4; ++mt)
#pragma unroll
        for (int nt = 0; nt < 2; ++nt)
#pragma unroll
            for (int v = 0; v < 16; ++v) acc[mt][nt][v] += bb[nt];

    if constexpr (EPI == 0) {  // Q: bias+RoPE+0.125 -> q_h[b][h][lq][hd]
        const float l2b = 13.287712379549449f;
        const float inv = exp2f(-((float)l31 * (1.0f / 32.0f)) * l2b);
        const int dv = 4096 / (nf > 1 ? nf : 1);
        _Float16* O = (_Float16*)Cp;
        const int head = nbase >> 6;
#pragma unroll
        for (int mt = 0; mt < 4; ++mt) {
#pragma unroll
            for (int v = 0; v < 16; ++v) {
                const int m = m0 + wm * 128 + mt * 32 + (v & 3) + 8 * (v >> 2) + 4 * hh;
                const int b = m >> 12, lq = m & 4095;
                if (nf > 1) {
                    const int pos = lq / dv;
                    float s, c;
                    __sincosf((float)pos * inv, &s, &c);
                    const float x1 = acc[mt][0][v], x2 = acc[mt][1][v];
                    acc[mt][0][v] = x1 * c - x2 * s;
                    acc[mt][1][v] = x2 * c + x1 * s;
                }
#pragma unroll
                for (int nt = 0; nt < 2; ++nt) {
                    const int hd = nt * 32 + l31;
                    O[(((size_t)(b * 16 + head)) * 4096 + lq) * 64 + hd] =
                        (_Float16)(acc[mt][nt][v] * 0.125f);
                }
            }
        }
    } else if constexpr (EPI == 1) {  // K/V fused (N=512)
        _Float16* kout = (_Float16*)Cp;
        _Float16* vout = kout + (size_t)4 * 4 * 256 * 64;
        if (nbase < 256) {
            const float l2b = 13.287712379549449f;
            const float inv = exp2f(-((float)l31 * (1.0f / 32.0f)) * l2b);
            const int dv = 256 / (nf > 1 ? nf : 1);
            const int kvh = nbase >> 6;
#pragma unroll
            for (int mt = 0; mt < 4; ++mt) {
#pragma unroll
                for (int v = 0; v < 16; ++v) {
                    const int m = m0 + wm * 128 + mt * 32 + (v & 3) + 8 * (v >> 2) + 4 * hh;
                    const int b = m >> 8, lkv = m & 255;
                    if (nf > 1) {
                        const int pos = lkv / dv;
                        float s, c;
                        __sincosf((float)pos * inv, &s, &c);
                        const float x1 = acc[mt][0][v], x2 = acc[mt][1][v];
                        acc[mt][0][v] = x1 * c - x2 * s;
                        acc[mt][1][v] = x2 * c + x1 * s;
                    }
#pragma unroll
                    for (int nt = 0; nt < 2; ++nt) {
                        const int hd = nt * 32 + l31;
                        kout[(((size_t)(b * 4 + kvh)) * 256 + lkv) * 64 + hd] =
                            (_Float16)acc[mt][nt][v];
                    }
                }
            }
        } else {
            const int kvh = (nbase - 256) >> 6;
#pragma unroll
            for (int mt = 0; mt < 4; ++mt) {
#pragma unroll
                for (int v = 0; v < 16; ++v) {
                    const int m = m0 + wm * 128 + mt * 32 + (v & 3) + 8 * (v >> 2) + 4 * hh;
                    const int b = m >> 8, lkv = m & 255;
                    // pi-permuted kv slot: swap the 16s bit below the 4s bits
                    const int s = (lkv & 0xE0) | ((lkv & 12) << 1) |
                                  ((lkv & 16) >> 2) | (lkv & 3);
#pragma unroll
                    for (int nt = 0; nt < 2; ++nt) {
                        const int hd = nt * 32 + l31;
                        vout[(((size_t)(b * 4 + kvh)) * 64 + hd) * 256 + s] =
                            (_Float16)acc[mt][nt][v];
                    }
                }
            }
        }
    } else {  // O-proj fp32
        float* O = (float*)Cp;
#pragma unroll
        for (int mt = 0; mt < 4; ++mt) {
#pragma unroll
            for (int v = 0; v < 16; ++v) {
                const int m = m0 + wm * 128 + mt * 32 + (v & 3) + 8 * (v >> 2) + 4 * hh;
#pragma unroll
                for (int nt = 0; nt < 2; ++nt)
                    O[(size_t)m * 1024 + nbase + nt * 32 + l31] = acc[mt][nt][v];
            }
        }
    }
}

// ---------------------------------------------------------------------------
// Attention v5.  Block = 4 waves = 256 q-rows of one (b,h); wave = 4 chunks
// of 16 q-rows.  K staged in LDS (32 KB, swizzled).  S^T = K @ Q^T.
// PV computed as O^T = V_pi @ P^T:
//   - P^T B-frag == in-lane repack of the exp'd S^T C-frag (no LDS, no shfl)
//   - V_pi A-frag == contiguous 16B global load (kv-permutation pi baked into
//     the V-projection store), L1/L2-hot
//   - O^T C-frag has q on l15 -> row inv-sum needs no shuffle; f16x4 stores.
// Register budget fits 128 (launch_bounds(256,4)) -> no spills, 4 blocks/CU.
// Grid (bh, qchunk): blockIdx%8 == bh%8 pins each K/V slab to one XCD L2.
// ---------------------------------------------------------------------------
__global__ __launch_bounds__(256, 4) void attn5(const _Float16* __restrict__ qh,
                                                const _Float16* __restrict__ kh,
                                                const _Float16* __restrict__ vp,
                                                _Float16* __restrict__ attn) {
    __shared__ _Float16 Ks[256 * 64];  // swizzled: chunk c of row r at c^(r&7)

    const int tid = threadIdx.x;
    const int w = tid >> 6, lane = tid & 63, quad = lane >> 4, l15 = lane & 15;
    const int bh = blockIdx.x, b = bh >> 4, h = bh & 15, kvh = h >> 2;
    const int q0 = blockIdx.y * 256;

    const _Float16* kb = kh + (size_t)(b * 4 + kvh) * 256 * 64;
    const _Float16* vb = vp + (size_t)(b * 4 + kvh) * 64 * 256;
    const _Float16* qb = qh + ((size_t)bh * 4096 + q0) * 64;

    // ---- stage K into LDS (2048 x 16B chunks, 8/thread), source-swizzled
#pragma unroll
    for (int i = 0; i < 8; ++i) {
        const int id = i * 256 + tid;
        const int r = id >> 3;
        const int c = (id & 7) ^ (r & 7);
        async_cp16(kb + (size_t)r * 64 + c * 8, Ks + i * 2048 + w * 512);
    }
    __syncthreads();

    const int sw = l15 & 7;        // read-side swizzle key (row&7 == l15&7)
    const int p0 = quad ^ sw;      // slot of k-chunk quad (hd 0..31)

#pragma unroll 1
    for (int chunk = 0; chunk < 4; ++chunk) {
        const int qrow = w * 64 + chunk * 16;

        // opaque V base: prevent LICM from hoisting 32 V loads across chunks
        const _Float16* vbl = vb;
        asm volatile("" : "+r"(vbl));

        // Q B-frags (softmax scale folded in at Q-proj)
        const _Float16* qp = qb + (size_t)(qrow + l15) * 64 + quad * 8;
        const f16x8 bq0 = *(const f16x8*)qp;
        const f16x8 bq1 = *(const f16x8*)(qp + 32);

        // S^T = K @ Q^T : lane holds S[q=l15][kv = t*16 + quad*4 + rr]
        f32x4 st[16];
#pragma unroll
        for (int t = 0; t < 16; ++t)
#pragma unroll
            for (int rr = 0; rr < 4; ++rr) st[t][rr] = 0.f;

#pragma unroll
        for (int t = 0; t < 16; ++t) {
            const int row = t * 16 + l15;
            const f16x8 ka0 = *(const f16x8*)&Ks[row * 64 + p0 * 8];
            const f16x8 ka1 = *(const f16x8*)&Ks[row * 64 + (p0 ^ 4) * 8];
            st[t] = MFMA16(ka0, bq0, st[t]);
            st[t] = MFMA16(ka1, bq1, st[t]);
        }

        // softmax over 256 kv (row q = l15 -> 2 shuffles)
        float rm = -1e30f;
#pragma unroll
        for (int t = 0; t < 16; ++t)
#pragma unroll
            for (int rr = 0; rr < 4; ++rr) rm = fmaxf(rm, st[t][rr]);
        rm = fmaxf(rm, __shfl_xor(rm, 16, 64));
        rm = fmaxf(rm, __shfl_xor(rm, 32, 64));

        float rs = 0.f;
#pragma unroll
        for (int t = 0; t < 16; ++t) {
#pragma unroll
            for (int rr = 0; rr < 4; ++rr) {
                st[t][rr] = __expf(st[t][rr] - rm);
                rs += st[t][rr];
            }
        }
        rs += __shfl_xor(rs, 16, 64);
        rs += __shfl_xor(rs, 32, 64);
        const float ir = 1.0f / rs;  // per-lane correct for q = l15

        // O^T = V_pi @ P^T : 4 hd-tiles, k = 256 in 8 chunks of 32
        f32x4 o[4];
#pragma unroll
        for (int nt = 0; nt < 4; ++nt)
#pragma unroll
            for (int rr = 0; rr < 4; ++rr) o[nt][rr] = 0.f;

#pragma unroll
        for (int c = 0; c < 8; ++c) {
            // P^T B-frag: slot (quad, j) <-> kv = 32c + 16*(j>>2) + 4*quad + (j&3)
            f16x8 pb;
#pragma unroll
            for (int j = 0; j < 8; ++j)
                pb[j] = (_Float16)st[2 * c + (j >> 2)][j & 3];
#pragma unroll
            for (int nt = 0; nt < 4; ++nt) {
                const f16x8 va = *(const f16x8*)(vbl + (size_t)(nt * 16 + l15) * 256 +
                                                 c * 32 + quad * 8);
                o[nt] = MFMA16(va, pb, o[nt]);
            }
        }

        // store: O^T C-frag: q = l15, hd = nt*16 + quad*4 + rr -> f16x4 packs
        const size_t rowbase = ((size_t)b * 4096 + q0 + qrow + l15) * 1024 + h * 64;
#pragma unroll
        for (int nt = 0; nt < 4; ++nt) {
            f16x4 ov;
#pragma unroll
            for (int rr = 0; rr < 4; ++rr) ov[rr] = (_Float16)(o[nt][rr] * ir);
            *(f16x4*)&attn[rowbase + nt * 16 + quad * 4] = ov;
        }
    }
}

// ---------------------------------------------------------------------------
extern "C" void kernel_launch(void* const* d_in, const int* in_sizes, int n_in,
                              void* d_out, int out_size, void* d_ws, size_t ws_size,
                              hipStream_t stream) {
    const float* patches = (const float*)d_in[0];
    const float* latents = (const float*)d_in[1];
    const float* Wq = (const float*)d_in[2];
    const float* bq = (const float*)d_in[3];
    const float* Wk = (const float*)d_in[4];
    const float* bk = (const float*)d_in[5];
    const float* Wv = (const float*)d_in[6];
    const float* bv = (const float*)d_in[7];
    const float* Wo = (const float*)d_in[8];
    const float* bo = (const float*)d_in[9];
    const int*   nf = (const int*)d_in[10];
    float* out = (float*)d_out;
    (void)in_sizes; (void)n_in; (void)out_size; (void)ws_size;

    char* p = (char*)d_ws;
    _Float16* WqT  = (_Float16*)p; p += (size_t)1024 * 1024 * 2;
    _Float16* WkvT = (_Float16*)p; p += (size_t)512 * 1024 * 2;
    _Float16* WoT  = (_Float16*)p; p += (size_t)1024 * 1024 * 2;
    float*    bkv  = (float*)p;    p += 4096;
    _Float16* p16  = (_Float16*)p; p += (size_t)4 * 4096 * 1024 * 2;
    _Float16* l16  = (_Float16*)p; p += (size_t)4 * 256 * 1024 * 2;
    _Float16* q_h  = (_Float16*)p; p += (size_t)4 * 16 * 4096 * 64 * 2;
    _Float16* k_h  = (_Float16*)p; p += (size_t)4 * 4 * 256 * 64 * 2;
    _Float16* v_pi = (_Float16*)p; p += (size_t)4 * 4 * 256 * 64 * 2;  // after k_h
    _Float16* attn_h = (_Float16*)p; p += (size_t)16384 * 1024 * 2;

    cvt_all<<<17408, 256, 0, stream>>>((const float4*)patches, (const float4*)latents,
                                       (f16x4*)p16, (f16x4*)l16);
    transpose_all<<<dim3(16, 16, 4), 256, 0, stream>>>(Wq, Wk, Wv, Wo, WqT, WkvT, WoT);
    catbias<<<1, 512, 0, stream>>>(bk, bv, bkv);

    gemm32<1><<<dim3(4, 4), 256, 0, stream>>>(l16, WkvT, bkv, k_h, nf);
    gemm32<0><<<dim3(8, 64), 256, 0, stream>>>(p16, WqT, bq, q_h, nf);

    attn5<<<dim3(64, 16), 256, 0, stream>>>(q_h, k_h, v_pi, attn_h);

    gemm32<2><<<dim3(8, 64), 256, 0, stream>>>(attn_h, WoT, bo, out, nf);
}